// Round 2
// baseline (153.098 us; speedup 1.0000x reference)
//
#include <hip/hip_runtime.h>
#include <stdint.h>

// AdaMoLE fused pipeline, bf16 MFMA.
//  N=8192 tokens, D_IN=4096, D_OUT=4096, E=8, r=16, SCALING=2.0, MAX_THR=1/8.
//
//  ws layout:
//    W1  : bf16, chunked [kc=64][row=144][k'=64], XOR-swizzled within 128B rows (1,179,648 B)
//    B2T : bf16, [o=4096][k=128], k=e*16+r, value = lora_B[e][o][r]*2.0      (1,048,576 B)
//    wh  : bf16, [n=8192][c=128], weighted h                                  (2,097,152 B)

typedef __bf16 bf16x8 __attribute__((ext_vector_type(8)));
typedef float f32x4 __attribute__((ext_vector_type(4)));
typedef __attribute__((address_space(1))) const void* gp_t;
typedef __attribute__((address_space(3))) void* lp_t;

__device__ __forceinline__ f32x4 mfma16(bf16x8 a, bf16x8 b, f32x4 c) {
  return __builtin_amdgcn_mfma_f32_16x16x32_bf16(a, b, c, 0, 0, 0);
}

// fp32 -> bf16 bits, round-to-nearest-even
__device__ __forceinline__ uint32_t bfbits(float f) {
  uint32_t u = __builtin_bit_cast(uint32_t, f);
  return (u + 0x7fffu + ((u >> 16) & 1u)) >> 16;
}

// ---------------- pack W1: rows 0..127 = lora_A (row = e*16+r), 128..135 = router_w,
// 136 = thr_w, 137..143 = zero pad. Stored per 64-wide K chunk, 128B rows,
// byte-offset XOR-swizzled by ((row&7)<<4) so kernel-1 can stage LDS linearly.
__global__ void pack_w1(const float* __restrict__ router_w,
                        const float* __restrict__ thr_w,
                        const float* __restrict__ lora_A,
                        uint32_t* __restrict__ W1) {
  int id = blockIdx.x * 256 + threadIdx.x;   // 64*144*32 threads
  int kp  = id & 31;                         // bf16 pair within chunk row
  int row = (id >> 5) % 144;
  int kc  = id / (32 * 144);
  int k   = kc * 64 + kp * 2;
  float v0 = 0.f, v1 = 0.f;
  if (row < 137) {
    const float* src = (row < 128) ? lora_A + (size_t)row * 4096
                     : (row < 136) ? router_w + (size_t)(row - 128) * 4096
                                   : thr_w;
    v0 = src[k]; v1 = src[k + 1];
  }
  uint32_t val = bfbits(v0) | (bfbits(v1) << 16);
  W1[(size_t)(kc * 144 + row) * 32 + (kp ^ ((row & 7) << 2))] = val;
}

// ---------------- pack B2T[o][k] = lora_B[e][o][r] * 2.0 (SCALING folded), bf16
__global__ void pack_b2(const float* __restrict__ lora_B, uint32_t* __restrict__ B2) {
  int id = blockIdx.x * 256 + threadIdx.x;   // 4096*64 threads
  int kp = id & 63;
  int o  = id >> 6;
  int k  = kp * 2;
  int e = k >> 4, r = k & 15;                // k even -> r<=14, pair stays in-expert
  const float* s = lora_B + (size_t)e * 4096 * 16 + (size_t)o * 16 + r;
  uint32_t val = bfbits(s[0] * 2.0f) | (bfbits(s[1] * 2.0f) << 16);
  B2[(size_t)o * 64 + kp] = val;
}

// ---------------- kernel 1: gating + h, fused. 16 tokens/block, 8 waves, grid 512
// (2 blocks/CU -> 4 waves/SIMD). C tile = [16 tok][144 cols]: cols 0..127 = h
// (expert e = col>>4), 128..135 = router logits, 136 = thr logit.
// Wave w owns col-tile w; wave 7 additionally owns tile 8 (gating cols).
// W staged async via global_load_lds (linear dest, matches W1 chunk layout).
__global__ __launch_bounds__(512) void k1_gate_h(
    const float* __restrict__ inp, const uint4* __restrict__ W1,
    const float* __restrict__ rb, const float* __restrict__ tb,
    unsigned short* __restrict__ wh) {
  __shared__ __align__(16) unsigned short Al[2][16 * 64];   // 4 KB
  __shared__ __align__(16) unsigned short Wl[2][144 * 64];  // 36 KB
  __shared__ float scores[16][16];
  __shared__ float wgt[16][8];
  __shared__ __align__(16) unsigned short whl[16 * 128];

  const int t = threadIdx.x;
  const int lane = t & 63;
  const int wave = t >> 6;
  const int n0 = blockIdx.x * 16;
  const int nt_cnt = (wave == 7) ? 2 : 1;

  f32x4 acc[2] = {};

  // A staging (threads 0..255): 16 rows x 64 k fp32 per chunk
  const int arow = (t >> 4) & 15;
  const int ac4  = (t & 15) * 4;
  const float* aptr = inp + (size_t)(n0 + arow) * 4096 + ac4;
  const int aoff = arow * 128 + ((ac4 * 2) ^ ((arow & 7) << 4)); // swizzled dest bytes

  // fragment read bases: A row = lane&15 -> row&7 == lane&7
  const int abase = (lane & 15) * 128;
  const int lswz  = (lane & 7) << 4;

  // async W stage: thread t copies uint4 idx {t, t+512, t<128: t+1024} linearly
#define STAGE_W(dbuf, kcn) do {                                                   \
    const uint4* wsrc = W1 + (size_t)(kcn) * 1152;                                \
    __builtin_amdgcn_global_load_lds((gp_t)(const void*)(wsrc + t),               \
        (lp_t)(void*)((char*)Wl[dbuf] + wave * 1024), 16, 0, 0);                  \
    __builtin_amdgcn_global_load_lds((gp_t)(const void*)(wsrc + t + 512),         \
        (lp_t)(void*)((char*)Wl[dbuf] + 8192 + wave * 1024), 16, 0, 0);           \
    if (t < 128)                                                                  \
      __builtin_amdgcn_global_load_lds((gp_t)(const void*)(wsrc + t + 1024),      \
          (lp_t)(void*)((char*)Wl[dbuf] + 16384 + wave * 1024), 16, 0, 0);        \
  } while (0)

  // ---- prologue: stage chunk 0 into buf 0
  {
    STAGE_W(0, 0);
    if (t < 256) {
      float4 av = *(const float4*)aptr;
      uint2 a2;
      a2.x = bfbits(av.x) | (bfbits(av.y) << 16);
      a2.y = bfbits(av.z) | (bfbits(av.w) << 16);
      *(uint2*)((char*)Al[0] + aoff) = a2;
    }
  }
  __syncthreads();

  for (int kc = 0; kc < 64; ++kc) {
    const int buf = kc & 1;
    const bool pre = (kc + 1 < 64);
    float4 av;
    if (pre) {  // issue next-chunk loads before compute (latency overlap)
      STAGE_W(buf ^ 1, kc + 1);
      if (t < 256) av = *(const float4*)(aptr + (size_t)(kc + 1) * 64);
    }
    const char* Ab = (const char*)Al[buf];
    const char* Wb = (const char*)Wl[buf];
#pragma unroll
    for (int ks = 0; ks < 2; ++ks) {
      const int koffb = ks * 64 + (lane >> 4) * 16;
      bf16x8 a = *(const bf16x8*)(Ab + abase + (koffb ^ lswz));
#pragma unroll
      for (int i = 0; i < 2; ++i) {
        if (i < nt_cnt) {
          const int wr = (wave + i) * 16 + (lane & 15);
          bf16x8 b = *(const bf16x8*)(Wb + wr * 128 + (koffb ^ lswz));
          acc[i] = mfma16(a, b, acc[i]);
        }
      }
    }
    if (pre && t < 256) {
      uint2 a2;
      a2.x = bfbits(av.x) | (bfbits(av.y) << 16);
      a2.y = bfbits(av.z) | (bfbits(av.w) << 16);
      *(uint2*)((char*)Al[buf ^ 1] + aoff) = a2;
    }
    __syncthreads();
  }

  // ---- epilogue: gating (wave 7's acc[1] holds cols 128..143)
  if (wave == 7) {
#pragma unroll
    for (int r = 0; r < 4; ++r)
      scores[(lane >> 4) * 4 + r][lane & 15] = acc[1][r];
  }
  __syncthreads();
  if (t < 16) {
    float l[9];
#pragma unroll
    for (int e = 0; e < 9; ++e) l[e] = scores[t][e];
    float mx = -3.4e38f;
#pragma unroll
    for (int e = 0; e < 8; ++e) { l[e] += rb[e]; mx = fmaxf(mx, l[e]); }
    float g[8], s = 0.f;
#pragma unroll
    for (int e = 0; e < 8; ++e) { g[e] = __expf(l[e] - mx); s += g[e]; }
    const float lt  = l[8] + tb[0];
    const float thr = 0.125f / (1.f + __expf(-lt));     // sigmoid * MAX_THRESHOLD
    const float inv = 1.f / s;
    float w[8], ws = 0.f;
#pragma unroll
    for (int e = 0; e < 8; ++e) { w[e] = fmaxf(g[e] * inv - thr, 0.f); ws += w[e]; }
    const float wn = (ws == 0.f) ? 1.f : ws;
#pragma unroll
    for (int e = 0; e < 8; ++e) wgt[t][e] = w[e] / wn;
  }
  __syncthreads();

  // weighted h -> LDS bounce (bf16); wave w == expert w
  {
    const int col = wave * 16 + (lane & 15);
#pragma unroll
    for (int r = 0; r < 4; ++r) {
      const int tok = (lane >> 4) * 4 + r;
      whl[tok * 128 + col] = (unsigned short)bfbits(acc[0][r] * wgt[tok][wave]);
    }
  }
  __syncthreads();
  if (t < 256) {  // coalesced wh write: 16 rows x 16 uint4
    const int row = t >> 4, seg = t & 15;
    ((uint4*)(wh + (size_t)(n0 + row) * 128))[seg] =
        ((const uint4*)(whl + row * 128))[seg];
  }
#undef STAGE_W
}

// ---------------- kernel 2: out = wh @ B2T (K=128), write-bound. No LDS.
// SWAPPED operands: acc = mfma(B2_frag, wh_frag) so the 4 acc regs of a lane
// hold 4 CONSECUTIVE out columns -> float4 (dwordx4) stores, 64B/token/instr.
// 64 tok x 128 col per block, grid 4096 (128 tok-blk x 32 col-blk).
__global__ __launch_bounds__(256) void k2_out(
    const unsigned short* __restrict__ wh,
    const unsigned short* __restrict__ B2,
    float* __restrict__ out) {
  const int t = threadIdx.x;
  const int lane = t & 63;
  const int wave = t >> 6;
  const int bid = blockIdx.x;
  const int tok0 = (bid >> 5) * 64 + wave * 16;
  const int col0 = (bid & 31) * 128;
  const int kq = lane >> 4;
  f32x4 acc[8] = {};
  uint4 a[4];
  const uint4* Ar = (const uint4*)(wh + (size_t)(tok0 + (lane & 15)) * 128);
#pragma unroll
  for (int ks = 0; ks < 4; ++ks) a[ks] = Ar[ks * 4 + kq];
#pragma unroll
  for (int nt = 0; nt < 8; ++nt) {
    const uint4* Br = (const uint4*)(B2 + (size_t)(col0 + nt * 16 + (lane & 15)) * 128);
#pragma unroll
    for (int ks = 0; ks < 4; ++ks) {
      bf16x8 b = __builtin_bit_cast(bf16x8, Br[ks * 4 + kq]);
      acc[nt] = mfma16(b, __builtin_bit_cast(bf16x8, a[ks]), acc[nt]);
    }
  }
  // store: token = tok0 + (lane&15); cols col0 + nt*16 + kq*4 .. +3 (16B aligned)
  float* orow = out + (size_t)(tok0 + (lane & 15)) * 4096 + col0 + kq * 4;
#pragma unroll
  for (int nt = 0; nt < 8; ++nt) {
    *(f32x4*)(orow + nt * 16) = acc[nt];
  }
}

extern "C" void kernel_launch(void* const* d_in, const int* in_sizes, int n_in,
                              void* d_out, int out_size, void* d_ws, size_t ws_size,
                              hipStream_t stream) {
  (void)in_sizes; (void)n_in; (void)out_size; (void)ws_size;
  const float* inp      = (const float*)d_in[0];
  const float* router_w = (const float*)d_in[1];
  const float* router_b = (const float*)d_in[2];
  const float* thr_w    = (const float*)d_in[3];
  const float* thr_b    = (const float*)d_in[4];
  const float* lora_A   = (const float*)d_in[5];
  const float* lora_B   = (const float*)d_in[6];
  float* out = (float*)d_out;

  char* ws = (char*)d_ws;
  uint32_t*       W1 = (uint32_t*)ws;                              // 1,179,648 B
  unsigned short* B2 = (unsigned short*)(ws + 1179648);            // 1,048,576 B
  unsigned short* wh = (unsigned short*)(ws + 1179648 + 1048576);  // 2,097,152 B

  pack_w1<<<1152, 256, 0, stream>>>(router_w, thr_w, lora_A, W1);
  pack_b2<<<1024, 256, 0, stream>>>(lora_B, (uint32_t*)B2);
  k1_gate_h<<<512, 512, 0, stream>>>(inp, (const uint4*)W1, router_b, thr_b, wh);
  k2_out<<<4096, 256, 0, stream>>>(wh, B2, out);
}

// Round 3
// 89.813 us; speedup vs baseline: 1.7046x; 1.7046x over previous
//
#include <hip/hip_runtime.h>
#include <stdint.h>

// AdaMoLE single fused kernel, bf16 MFMA.
//  N=8192 tokens, D_IN=4096, D_OUT=4096, E=8, r=16, SCALING=2.0, MAX_THR=1/8.
//
//  ws layout (frag-major packed weights; a wave's MFMA B-fragment = one
//  contiguous 1KB load = uint4 per lane):
//   W1p : [ct=9][k32=128][lane=64] x 16B   rows ct*16+(l&15): 0..127 lora_A
//         (row=e*16+r), 128..135 router_w, 136 thr_w, 137..143 zero. 1,179,648 B
//   B2p : [ct=256][ks=4][lane=64] x 16B    col ct*16+(l&15), k=ks*32+(l>>4)*8,
//         value lora_B[k>>4][col][k&15] * 2.0 (SCALING folded).     1,048,576 B

typedef __bf16 bf16x8 __attribute__((ext_vector_type(8)));
typedef float f32x4 __attribute__((ext_vector_type(4)));

__device__ __forceinline__ f32x4 mfma16(bf16x8 a, bf16x8 b, f32x4 c) {
  return __builtin_amdgcn_mfma_f32_16x16x32_bf16(a, b, c, 0, 0, 0);
}
__device__ __forceinline__ uint32_t bfbits(float f) {
  uint32_t u = __builtin_bit_cast(uint32_t, f);
  return (u + 0x7fffu + ((u >> 16) & 1u)) >> 16;
}
__device__ __forceinline__ uint32_t pk2(float a, float b) {
  return bfbits(a) | (bfbits(b) << 16);
}

// ---------------- pack W1 frag-major
__global__ void pack_w1p(const float* __restrict__ rw, const float* __restrict__ tw,
                         const float* __restrict__ la, uint4* __restrict__ W1p) {
  int id = blockIdx.x * 256 + threadIdx.x;            // 9*128*64 = 73728
  int lane = id & 63, k32 = (id >> 6) & 127, ct = id >> 13;
  int row = ct * 16 + (lane & 15);
  int col = k32 * 32 + (lane >> 4) * 8;
  const float* src = nullptr;
  if (row < 128)      src = la + (size_t)row * 4096 + col;
  else if (row < 136) src = rw + (size_t)(row - 128) * 4096 + col;
  else if (row == 136) src = tw + col;
  float v[8];
#pragma unroll
  for (int j = 0; j < 8; ++j) v[j] = src ? src[j] : 0.f;
  uint4 u;
  u.x = pk2(v[0], v[1]); u.y = pk2(v[2], v[3]);
  u.z = pk2(v[4], v[5]); u.w = pk2(v[6], v[7]);
  W1p[(size_t)(ct * 128 + k32) * 64 + lane] = u;
}

// ---------------- pack B2 frag-major (SCALING=2 folded)
__global__ void pack_b2p(const float* __restrict__ lb, uint4* __restrict__ B2p) {
  int id = blockIdx.x * 256 + threadIdx.x;            // 256*4*64 = 65536
  int lane = id & 63, ks = (id >> 6) & 3, ct = id >> 8;
  int o = ct * 16 + (lane & 15);
  int k0 = ks * 32 + (lane >> 4) * 8;                 // k0&15 in {0,8}: 8 floats same (e,o)
  const float* s = lb + (size_t)(k0 >> 4) * 65536 + (size_t)o * 16 + (k0 & 15);
  uint4 u;
  u.x = pk2(s[0] * 2.f, s[1] * 2.f); u.y = pk2(s[2] * 2.f, s[3] * 2.f);
  u.z = pk2(s[4] * 2.f, s[5] * 2.f); u.w = pk2(s[6] * 2.f, s[7] * 2.f);
  B2p[(size_t)(ct * 4 + ks) * 64 + lane] = u;
}

// ---------------- fused: gating + h + out. 32 tok/block, 8 waves, grid 256.
__global__ __launch_bounds__(512, 2) void k_fused(
    const float* __restrict__ inp, const uint4* __restrict__ W1p,
    const uint4* __restrict__ B2p, const float* __restrict__ rb,
    const float* __restrict__ tb, float* __restrict__ out) {
  // [0,64K): phase1 A dbuf (2x32KB) / epi reduction (16KB) / phase2 bounce (64KB)
  // [64K, +8K): whl bf16 [32 tok][128 k] swizzled; then scores[32][16], wgt[32][8]
  __shared__ __align__(16) char smem[76800];
  char* const Ab  = smem;
  char* const whl = smem + 65536;
  float* const scores = (float*)(smem + 73728);
  float* const wgt    = (float*)(smem + 75776);

  const int t = threadIdx.x;
  const int lane = t & 63;
  const int w = t >> 6;
  const int l15 = lane & 15;
  const int lq = lane >> 4;
  const int n0 = blockIdx.x * 32;

  // ===== phase 1: C[32 tok][144] over K=4096, 8 chunks of 512.
  // wave w owns col-tile w (2 token-tiles) + a K-slice of tile 8 (gating).
  const int srow = t >> 5;                 // A staging: rows {srow, srow+16}
  const int scol = (t & 31) * 4;           // cols scol + j*128 (512B contig/wave-instr)
  const float* ap0 = inp + (size_t)(n0 + srow) * 4096 + scol;
  const float* ap1 = ap0 + (size_t)16 * 4096;
  const int sx = (srow & 7) << 4;
  const int rx = (l15 & 7) << 4;

  f32x4 accO[2] = {};
  f32x4 acc8[2] = {};
  float4 av[2][4];

#pragma unroll
  for (int j = 0; j < 4; ++j) {
    av[0][j] = *(const float4*)(ap0 + j * 128);
    av[1][j] = *(const float4*)(ap1 + j * 128);
  }
#pragma unroll
  for (int r = 0; r < 2; ++r) {
    char* d2 = Ab + (r * 16 + srow) * 1024;
#pragma unroll
    for (int j = 0; j < 4; ++j) {
      uint2 u; u.x = pk2(av[r][j].x, av[r][j].y); u.y = pk2(av[r][j].z, av[r][j].w);
      *(uint2*)(d2 + (((t & 31) * 8 + j * 256) ^ sx)) = u;
    }
  }
  __syncthreads();

  for (int c = 0; c < 8; ++c) {
    const int buf = c & 1;
    if (c < 7) {
#pragma unroll
      for (int j = 0; j < 4; ++j) {
        av[0][j] = *(const float4*)(ap0 + (c + 1) * 512 + j * 128);
        av[1][j] = *(const float4*)(ap1 + (c + 1) * 512 + j * 128);
      }
    }
    const char* A0 = Ab + buf * 32768;
    const uint4* wown = W1p + (size_t)(w * 128 + c * 16) * 64 + lane;
#pragma unroll
    for (int ks = 0; ks < 16; ++ks) {
      bf16x8 b = __builtin_bit_cast(bf16x8, wown[ks * 64]);
      bf16x8 a0 = *(const bf16x8*)(A0 + l15 * 1024 + ((ks * 64 + lq * 16) ^ rx));
      bf16x8 a1 = *(const bf16x8*)(A0 + (16 + l15) * 1024 + ((ks * 64 + lq * 16) ^ rx));
      accO[0] = mfma16(a0, b, accO[0]);
      accO[1] = mfma16(a1, b, accO[1]);
    }
    const uint4* w8 = W1p + (size_t)(8 * 128 + c * 16) * 64 + lane;
#pragma unroll
    for (int ii = 0; ii < 2; ++ii) {
      const int ks8 = w + ii * 8;          // K-split of tile 8 across waves
      bf16x8 b8 = __builtin_bit_cast(bf16x8, w8[ks8 * 64]);
      bf16x8 a0 = *(const bf16x8*)(A0 + l15 * 1024 + ((ks8 * 64 + lq * 16) ^ rx));
      bf16x8 a1 = *(const bf16x8*)(A0 + (16 + l15) * 1024 + ((ks8 * 64 + lq * 16) ^ rx));
      acc8[0] = mfma16(a0, b8, acc8[0]);
      acc8[1] = mfma16(a1, b8, acc8[1]);
    }
    if (c < 7) {
      char* dst = Ab + (buf ^ 1) * 32768;
#pragma unroll
      for (int r = 0; r < 2; ++r) {
        char* d2 = dst + (r * 16 + srow) * 1024;
#pragma unroll
        for (int j = 0; j < 4; ++j) {
          uint2 u; u.x = pk2(av[r][j].x, av[r][j].y); u.y = pk2(av[r][j].z, av[r][j].w);
          *(uint2*)(d2 + (((t & 31) * 8 + j * 256) ^ sx)) = u;
        }
      }
    }
    __syncthreads();
  }

  // ===== epilogue: reduce tile-8 partials, gate, build whl
#pragma unroll
  for (int tt = 0; tt < 2; ++tt)
    *(f32x4*)(Ab + ((w * 2 + tt) * 64 + lane) * 16) = acc8[tt];
  __syncthreads();
  {
    const int tt = t >> 8, l = (t >> 2) & 63, r_ = t & 3;
    float s = 0.f;
#pragma unroll
    for (int w2 = 0; w2 < 8; ++w2)
      s += *(const float*)(Ab + (((w2 * 2 + tt) * 64 + l) * 4 + r_) * 4);
    scores[(tt * 16 + (l >> 4) * 4 + r_) * 16 + (l & 15)] = s;
  }
  __syncthreads();
  if (t < 32) {
    float l_[9];
#pragma unroll
    for (int e = 0; e < 9; ++e) l_[e] = scores[t * 16 + e];
    float mx = -3.4e38f;
#pragma unroll
    for (int e = 0; e < 8; ++e) { l_[e] += rb[e]; mx = fmaxf(mx, l_[e]); }
    float g[8], s = 0.f;
#pragma unroll
    for (int e = 0; e < 8; ++e) { g[e] = __expf(l_[e] - mx); s += g[e]; }
    const float thr = 0.125f / (1.f + __expf(-(l_[8] + tb[0])));
    const float inv = 1.f / s;
    float wv[8], ws = 0.f;
#pragma unroll
    for (int e = 0; e < 8; ++e) { wv[e] = fmaxf(g[e] * inv - thr, 0.f); ws += wv[e]; }
    const float wn = (ws == 0.f) ? 1.f : ws;
#pragma unroll
    for (int e = 0; e < 8; ++e) wgt[t * 8 + e] = wv[e] / wn;
  }
  __syncthreads();
#pragma unroll
  for (int tt = 0; tt < 2; ++tt) {
#pragma unroll
    for (int r_ = 0; r_ < 4; ++r_) {
      const int tok = tt * 16 + lq * 4 + r_;
      *(unsigned short*)(whl + tok * 256 + (((w * 16 + l15) * 2) ^ ((tok & 7) << 4))) =
          (unsigned short)bfbits(accO[tt][r_] * wgt[tok * 8 + w]);
    }
  }
  __syncthreads();

  // ===== phase 2: out[32 tok][4096] = whl @ B2p^T, 8 passes of 512 cols.
  // swapped MFMA: lane's 4 acc regs = 4 consecutive out cols.
  bf16x8 pa0[4], pa1[4];
#pragma unroll
  for (int ks = 0; ks < 4; ++ks) {
    pa0[ks] = *(const bf16x8*)(whl + l15 * 256 + ((ks * 64 + lq * 16) ^ rx));
    pa1[ks] = *(const bf16x8*)(whl + (16 + l15) * 256 + ((ks * 64 + lq * 16) ^ rx));
  }
  const int row = t >> 4, seg = t & 15;
  float* orow = out + (size_t)(n0 + row) * 4096 + seg * 4;
  for (int p = 0; p < 8; ++p) {
    f32x4 acc0[4] = {}, acc1[4] = {};
    const uint4* bp = B2p + (size_t)((p * 32 + w * 4) * 4) * 64 + lane;
#pragma unroll
    for (int i = 0; i < 4; ++i) {
#pragma unroll
      for (int ks = 0; ks < 4; ++ks) {
        bf16x8 b = __builtin_bit_cast(bf16x8, bp[(i * 4 + ks) * 64]);
        acc0[i] = mfma16(b, pa0[ks], acc0[i]);
        acc1[i] = mfma16(b, pa1[ks], acc1[i]);
      }
    }
    // bounce -> LDS [tok][512 f32], swizzled
#pragma unroll
    for (int i = 0; i < 4; ++i) {
      *(f32x4*)(Ab + l15 * 2048 + ((w * 256 + i * 64 + lq * 16) ^ rx)) = acc0[i];
      *(f32x4*)(Ab + (16 + l15) * 2048 + ((w * 256 + i * 64 + lq * 16) ^ rx)) = acc1[i];
    }
    asm volatile("s_waitcnt lgkmcnt(0)" ::: "memory");
    __builtin_amdgcn_sched_barrier(0);
    __builtin_amdgcn_s_barrier();          // LDS-only barrier: stores keep streaming
#pragma unroll
    for (int j = 0; j < 8; ++j) {
      f32x4 v = *(const f32x4*)(Ab + row * 2048 + ((seg * 16 + j * 256) ^ ((row & 7) << 4)));
      __builtin_nontemporal_store(v, (f32x4*)(orow + p * 512 + j * 64));
    }
    asm volatile("s_waitcnt lgkmcnt(0)" ::: "memory");
    __builtin_amdgcn_sched_barrier(0);
    __builtin_amdgcn_s_barrier();
  }
}

extern "C" void kernel_launch(void* const* d_in, const int* in_sizes, int n_in,
                              void* d_out, int out_size, void* d_ws, size_t ws_size,
                              hipStream_t stream) {
  (void)in_sizes; (void)n_in; (void)out_size; (void)ws_size;
  const float* inp      = (const float*)d_in[0];
  const float* router_w = (const float*)d_in[1];
  const float* router_b = (const float*)d_in[2];
  const float* thr_w    = (const float*)d_in[3];
  const float* thr_b    = (const float*)d_in[4];
  const float* lora_A   = (const float*)d_in[5];
  const float* lora_B   = (const float*)d_in[6];
  float* out = (float*)d_out;

  char* ws = (char*)d_ws;
  uint4* W1p = (uint4*)ws;                      // 1,179,648 B
  uint4* B2p = (uint4*)(ws + 1179648);          // 1,048,576 B

  pack_w1p<<<288, 256, 0, stream>>>(router_w, thr_w, lora_A, W1p);
  pack_b2p<<<256, 256, 0, stream>>>(lora_B, B2p);
  k_fused<<<256, 512, 0, stream>>>(inp, W1p, B2p, router_b, thr_b, out);
}

// Round 4
// 84.219 us; speedup vs baseline: 1.8179x; 1.0664x over previous
//
#include <hip/hip_runtime.h>
#include <stdint.h>

// AdaMoLE single fused kernel, bf16 MFMA. 16 tok/block, grid 512 (2 blocks/CU).
//  N=8192 tokens, D_IN=4096, D_OUT=4096, E=8, r=16, SCALING=2.0, MAX_THR=1/8.
//
//  ws layout (frag-major packed weights; a wave's MFMA B-fragment = one
//  contiguous 1KB load = uint4 per lane):
//   W1p : [ct=9][k32=128][lane=64] x 16B   rows ct*16+(l&15): 0..127 lora_A
//         (row=e*16+r), 128..135 router_w, 136 thr_w, 137..143 zero. 1,179,648 B
//   B2p : [ct=256][ks=4][lane=64] x 16B    col ct*16+(l&15), k=ks*32+(l>>4)*8,
//         value lora_B[k>>4][col][k&15] * 2.0 (SCALING folded).     1,048,576 B

typedef __bf16 bf16x8 __attribute__((ext_vector_type(8)));
typedef float f32x4 __attribute__((ext_vector_type(4)));

__device__ __forceinline__ f32x4 mfma16(bf16x8 a, bf16x8 b, f32x4 c) {
  return __builtin_amdgcn_mfma_f32_16x16x32_bf16(a, b, c, 0, 0, 0);
}
__device__ __forceinline__ uint32_t bfbits(float f) {
  uint32_t u = __builtin_bit_cast(uint32_t, f);
  return (u + 0x7fffu + ((u >> 16) & 1u)) >> 16;
}
__device__ __forceinline__ uint32_t pk2(float a, float b) {
  return bfbits(a) | (bfbits(b) << 16);
}

// ---------------- pack W1 frag-major
__global__ void pack_w1p(const float* __restrict__ rw, const float* __restrict__ tw,
                         const float* __restrict__ la, uint4* __restrict__ W1p) {
  int id = blockIdx.x * 256 + threadIdx.x;            // 9*128*64 = 73728
  int lane = id & 63, k32 = (id >> 6) & 127, ct = id >> 13;
  int row = ct * 16 + (lane & 15);
  int col = k32 * 32 + (lane >> 4) * 8;
  const float* src = nullptr;
  if (row < 128)      src = la + (size_t)row * 4096 + col;
  else if (row < 136) src = rw + (size_t)(row - 128) * 4096 + col;
  else if (row == 136) src = tw + col;
  float v[8];
#pragma unroll
  for (int j = 0; j < 8; ++j) v[j] = src ? src[j] : 0.f;
  uint4 u;
  u.x = pk2(v[0], v[1]); u.y = pk2(v[2], v[3]);
  u.z = pk2(v[4], v[5]); u.w = pk2(v[6], v[7]);
  W1p[(size_t)(ct * 128 + k32) * 64 + lane] = u;
}

// ---------------- pack B2 frag-major (SCALING=2 folded)
__global__ void pack_b2p(const float* __restrict__ lb, uint4* __restrict__ B2p) {
  int id = blockIdx.x * 256 + threadIdx.x;            // 256*4*64 = 65536
  int lane = id & 63, ks = (id >> 6) & 3, ct = id >> 8;
  int o = ct * 16 + (lane & 15);
  int k0 = ks * 32 + (lane >> 4) * 8;                 // k0&15 in {0,8}: 8 floats same (e,o)
  const float* s = lb + (size_t)(k0 >> 4) * 65536 + (size_t)o * 16 + (k0 & 15);
  uint4 u;
  u.x = pk2(s[0] * 2.f, s[1] * 2.f); u.y = pk2(s[2] * 2.f, s[3] * 2.f);
  u.z = pk2(s[4] * 2.f, s[5] * 2.f); u.w = pk2(s[6] * 2.f, s[7] * 2.f);
  B2p[(size_t)(ct * 4 + ks) * 64 + lane] = u;
}

// ---------------- fused: gating + h + out. 16 tok/block, 8 waves, grid 512.
// LDS ~38KB -> 2+ blocks/CU (grid gives 2). Phase-2 bounce reuses A region
// with 2064B padded row stride (bank-conflict floor on both sides).
__global__ __launch_bounds__(512, 4) void k_fused(
    const float* __restrict__ inp, const uint4* __restrict__ W1p,
    const uint4* __restrict__ B2p, const float* __restrict__ rb,
    const float* __restrict__ tb, float* __restrict__ out) {
  // [0,33024): phase1 A dbuf (2x16KB) / epi partials (8KB) / phase2 bounce
  //            (16 rows x 2064B). [33024,+4K): whl bf16 [16][128] swizzled.
  // [37120,+1K): scores[16][16]. [38144,+512): wgt[16][8].
  __shared__ __align__(16) char smem[38656];
  char* const Ab  = smem;
  char* const whl = smem + 33024;
  float* const scores = (float*)(smem + 37120);
  float* const wgt    = (float*)(smem + 38144);

  const int t = threadIdx.x;
  const int lane = t & 63;
  const int w = t >> 6;
  const int l15 = lane & 15;
  const int lq = lane >> 4;
  const int n0 = blockIdx.x * 16;
  const int rx = (l15 & 7) << 4;

  // ===== phase 1: C[16 tok][144] over K=4096, 8 chunks of 512.
  // wave w owns col-tile w; tile 8 (gating) K-split across waves.
  const int srow = t >> 5;                 // A staging row (0..15)
  const int scol = (t & 31) * 4;           // fp32 col; cols scol + j*128
  const float* ap = inp + (size_t)(n0 + srow) * 4096 + scol;
  const int sx = (srow & 7) << 4;

  f32x4 accO = {};
  f32x4 acc8 = {};
  float4 av[4];

#pragma unroll
  for (int j = 0; j < 4; ++j) av[j] = *(const float4*)(ap + j * 128);
  {
    char* d2 = Ab + srow * 1024;
#pragma unroll
    for (int j = 0; j < 4; ++j) {
      uint2 u; u.x = pk2(av[j].x, av[j].y); u.y = pk2(av[j].z, av[j].w);
      *(uint2*)(d2 + (((t & 31) * 8 + j * 256) ^ sx)) = u;
    }
  }
  __syncthreads();

  for (int c = 0; c < 8; ++c) {
    const int buf = c & 1;
    if (c < 7) {
#pragma unroll
      for (int j = 0; j < 4; ++j)
        av[j] = *(const float4*)(ap + (c + 1) * 512 + j * 128);
    }
    const char* A0 = Ab + buf * 16384;
    const uint4* wown = W1p + (size_t)(w * 128 + c * 16) * 64 + lane;
#pragma unroll
    for (int ks = 0; ks < 16; ++ks) {
      bf16x8 b = __builtin_bit_cast(bf16x8, wown[ks * 64]);
      bf16x8 a = *(const bf16x8*)(A0 + l15 * 1024 + ((ks * 64 + lq * 16) ^ rx));
      accO = mfma16(a, b, accO);
    }
    const uint4* w8 = W1p + (size_t)(8 * 128 + c * 16) * 64 + lane;
#pragma unroll
    for (int ii = 0; ii < 2; ++ii) {
      const int ks8 = w + ii * 8;          // K-split of tile 8 across waves
      bf16x8 b8 = __builtin_bit_cast(bf16x8, w8[ks8 * 64]);
      bf16x8 a = *(const bf16x8*)(A0 + l15 * 1024 + ((ks8 * 64 + lq * 16) ^ rx));
      acc8 = mfma16(a, b8, acc8);
    }
    if (c < 7) {
      char* d2 = Ab + (buf ^ 1) * 16384 + srow * 1024;
#pragma unroll
      for (int j = 0; j < 4; ++j) {
        uint2 u; u.x = pk2(av[j].x, av[j].y); u.y = pk2(av[j].z, av[j].w);
        *(uint2*)(d2 + (((t & 31) * 8 + j * 256) ^ sx)) = u;
      }
    }
    __syncthreads();
  }

  // ===== epilogue: reduce tile-8 partials, gate, build whl
  *(f32x4*)(Ab + (size_t)(w * 64 + lane) * 16) = acc8;
  __syncthreads();
  if (t < 256) {
    const int l = t >> 2, r_ = t & 3;
    float s = 0.f;
#pragma unroll
    for (int w2 = 0; w2 < 8; ++w2)
      s += ((const float*)Ab)[(w2 * 64 + l) * 4 + r_];
    scores[((l >> 4) * 4 + r_) * 16 + (l & 15)] = s;
  }
  __syncthreads();
  if (t < 16) {
    float l_[9];
#pragma unroll
    for (int e = 0; e < 9; ++e) l_[e] = scores[t * 16 + e];
    float mx = -3.4e38f;
#pragma unroll
    for (int e = 0; e < 8; ++e) { l_[e] += rb[e]; mx = fmaxf(mx, l_[e]); }
    float g[8], s = 0.f;
#pragma unroll
    for (int e = 0; e < 8; ++e) { g[e] = __expf(l_[e] - mx); s += g[e]; }
    const float thr = 0.125f / (1.f + __expf(-(l_[8] + tb[0])));
    const float inv = 1.f / s;
    float wv[8], ws = 0.f;
#pragma unroll
    for (int e = 0; e < 8; ++e) { wv[e] = fmaxf(g[e] * inv - thr, 0.f); ws += wv[e]; }
    const float wn = (ws == 0.f) ? 1.f : ws;
#pragma unroll
    for (int e = 0; e < 8; ++e) wgt[t * 8 + e] = wv[e] / wn;
  }
  __syncthreads();
  // weighted h -> whl (wave w == expert w), swizzled by token
#pragma unroll
  for (int r_ = 0; r_ < 4; ++r_) {
    const int tok = lq * 4 + r_;
    *(unsigned short*)(whl + tok * 256 + (((w * 16 + l15) * 2) ^ ((tok & 7) << 4))) =
        (unsigned short)bfbits(accO[r_] * wgt[tok * 8 + w]);
  }
  __syncthreads();

  // ===== phase 2: out[16 tok][4096] = whl @ B2p^T, 8 passes of 512 cols.
  // swapped MFMA: lane's 4 acc regs = 4 consecutive out cols; token = l15.
  bf16x8 pa[4];
#pragma unroll
  for (int ks = 0; ks < 4; ++ks)
    pa[ks] = *(const bf16x8*)(whl + l15 * 256 + ((ks * 64 + lq * 16) ^ rx));

  const int row = t >> 5, seg = t & 31;    // store: 2048B/row, 32 segs x 4 j
  float* orow = out + (size_t)(n0 + row) * 4096 + seg * 4;
  for (int p = 0; p < 8; ++p) {
    f32x4 acc[4] = {};
    const uint4* bp = B2p + (size_t)((p * 32 + w * 4) * 4) * 64 + lane;
#pragma unroll
    for (int i = 0; i < 4; ++i) {
#pragma unroll
      for (int ks = 0; ks < 4; ++ks) {
        bf16x8 b = __builtin_bit_cast(bf16x8, bp[(i * 4 + ks) * 64]);
        acc[i] = mfma16(b, pa[ks], acc[i]);
      }
    }
    // bounce -> LDS [tok][512 f32], padded row stride 2064B
#pragma unroll
    for (int i = 0; i < 4; ++i)
      *(f32x4*)(Ab + l15 * 2064 + (w * 4 + i) * 64 + lq * 16) = acc[i];
    asm volatile("s_waitcnt lgkmcnt(0)" ::: "memory");
    __builtin_amdgcn_sched_barrier(0);
    __builtin_amdgcn_s_barrier();          // LDS-only barrier: stores keep streaming
#pragma unroll
    for (int j = 0; j < 4; ++j) {
      f32x4 v = *(const f32x4*)(Ab + row * 2064 + (seg + j * 32) * 16);
      __builtin_nontemporal_store(v, (f32x4*)(orow + p * 512 + j * 128));
    }
    asm volatile("s_waitcnt lgkmcnt(0)" ::: "memory");
    __builtin_amdgcn_sched_barrier(0);
    __builtin_amdgcn_s_barrier();
  }
}

extern "C" void kernel_launch(void* const* d_in, const int* in_sizes, int n_in,
                              void* d_out, int out_size, void* d_ws, size_t ws_size,
                              hipStream_t stream) {
  (void)in_sizes; (void)n_in; (void)out_size; (void)ws_size;
  const float* inp      = (const float*)d_in[0];
  const float* router_w = (const float*)d_in[1];
  const float* router_b = (const float*)d_in[2];
  const float* thr_w    = (const float*)d_in[3];
  const float* thr_b    = (const float*)d_in[4];
  const float* lora_A   = (const float*)d_in[5];
  const float* lora_B   = (const float*)d_in[6];
  float* out = (float*)d_out;

  char* ws = (char*)d_ws;
  uint4* W1p = (uint4*)ws;                      // 1,179,648 B
  uint4* B2p = (uint4*)(ws + 1179648);          // 1,048,576 B

  pack_w1p<<<288, 256, 0, stream>>>(router_w, thr_w, lora_A, W1p);
  pack_b2p<<<256, 256, 0, stream>>>(lora_B, B2p);
  k_fused<<<512, 512, 0, stream>>>(inp, W1p, B2p, router_b, thr_b, out);
}